// Round 1
// 223.505 us; speedup vs baseline: 1.0772x; 1.0772x over previous
//
#include <hip/hip_runtime.h>
#include <hip/hip_bf16.h>

typedef __attribute__((ext_vector_type(8))) _Float16 f16x8;
typedef __attribute__((ext_vector_type(4))) float f32x4;
typedef unsigned short u16;
typedef unsigned int u32;

#define S_LEN 2048
#define NH    16
#define DK    64
#define DMODEL 1024
#define LSTR  40   // LDS row stride (f16 elems) for GEMM tiles
#define LOG2E 1.44269504f

union F16U { _Float16 h; u16 u; };
__device__ __forceinline__ u16 f2h(float f) {
    F16U v; v.h = (_Float16)f; return v.u;
}

// ------------------------- bias table --------------------------------------
// Integer-exact replica of the reference fp32 bucket math; thresholds
// {12,16,23,32,46,64,91} verified against fp32 log arithmetic.
// NOTE: table is pre-scaled by log2(e) — attn softmax runs in exp2 domain.
__global__ __launch_bounds__(256) void bias_table_kernel(
    const float* __restrict__ rel_emb, float* __restrict__ tab)
{
    int idx = blockIdx.x * 256 + threadIdx.x;   // 0..65535
    int h = idx >> 12;
    int t = idx & 4095;
    int rp = t - 2048;          // rel_pos = k - q
    int n = -rp;                // q - k
    int ret = 0;
    if (n < 0) { ret = 16; n = -n; }
    int inner;
    if (n < 8) {
        inner = n;
    } else {
        inner = 8 + (n >= 12) + (n >= 16) + (n >= 23) + (n >= 32)
                  + (n >= 46) + (n >= 64) + (n >= 91);
        if (inner > 15) inner = 15;
    }
    tab[h * 4096 + t] = rel_emb[(ret + inner) * NH + h] * LOG2E;
}

// ---------------- X convert: fp32 -> fp16 ----------------------------------
__global__ __launch_bounds__(256) void convert_x(
    const float* __restrict__ X, u16* __restrict__ Xf)
{
    long i8 = ((long)blockIdx.x * 256 + threadIdx.x) * 8;
    float4 a = *(const float4*)&X[i8];
    float4 b = *(const float4*)&X[i8 + 4];
    *(ushort4*)&Xf[i8] =
        make_ushort4(f2h(a.x), f2h(a.y), f2h(a.z), f2h(a.w));
    *(ushort4*)&Xf[i8 + 4] =
        make_ushort4(f2h(b.x), f2h(b.y), f2h(b.z), f2h(b.w));
}

// ---------------- weight convert + transpose: W[k][n] -> WT fp16 [n][k] ----
__global__ __launch_bounds__(256) void convert_wT(
    const float* __restrict__ Wq, const float* __restrict__ Wk,
    const float* __restrict__ Wv, const float* __restrict__ Wo,
    u16* __restrict__ WT)
{
    const float* src = (blockIdx.z == 0) ? Wq : (blockIdx.z == 1) ? Wk
                     : (blockIdx.z == 2) ? Wv : Wo;
    u16* dT = WT + (long)blockIdx.z * 1048576;
    __shared__ __align__(16) float T[64 * 68];
    const int k0 = blockIdx.y * 64, n0 = blockIdx.x * 64;
    const int tid = threadIdx.x;
    #pragma unroll
    for (int u = 0; u < 4; u++) {
        int w = tid + u * 256;
        int r = w >> 4, c4 = (w & 15) * 4;
        *(float4*)&T[r * 68 + c4] =
            *(const float4*)&src[(long)(k0 + r) * DMODEL + n0 + c4];
    }
    __syncthreads();
    #pragma unroll
    for (int u = 0; u < 4; u++) {
        int w = tid + u * 256;
        int n = w >> 4, kc = (w & 15) * 4;
        *(ushort4*)&dT[(long)(n0 + n) * DMODEL + k0 + kc] = make_ushort4(
            f2h(T[(kc + 0) * 68 + n]), f2h(T[(kc + 1) * 68 + n]),
            f2h(T[(kc + 2) * 68 + n]), f2h(T[(kc + 3) * 68 + n]));
    }
}

// ------------------------- MFMA QKV GEMM (fp16, 1-pass) --------------------
// z=0: Q -> [B,H,S,Dk]; z=1: K -> [B,H,S,Dk]; z=2: V -> V^T [B,H,Dk,S].
// Async-STAGE split (T14): next K-slice prefetched to regs during MFMA,
// written to LDS after the read-barrier.
__global__ __launch_bounds__(256, 3) void gemm_qkv_mfma(
    const u16* __restrict__ Xf, const u16* __restrict__ WT,
    u16* __restrict__ Qf, u16* __restrict__ Kf, u16* __restrict__ VT)
{
    const int z = blockIdx.z;
    const u16* BT = WT + (long)z * 1048576;

    __shared__ __align__(16) u16 Ah[128 * LSTR], Bh[128 * LSTR];

    const int tid = threadIdx.x;
    const int wv = tid >> 6, lane = tid & 63;
    const int g = lane >> 4, li = lane & 15;
    const int wr = wv >> 1, wc = wv & 1;
    const int bm = blockIdx.y * 128, bn = blockIdx.x * 128;

    const int srow = tid >> 2, sq8 = (tid & 3) * 8;
    const u16* As0 = &Xf[(long)(bm + srow) * DMODEL + sq8];
    const u16* As1 = &Xf[(long)(bm + srow + 64) * DMODEL + sq8];
    const u16* Bs0 = &BT[(long)(bn + srow) * DMODEL + sq8];
    const u16* Bs1 = &BT[(long)(bn + srow + 64) * DMODEL + sq8];
    u16* AL0 = &Ah[srow * LSTR + sq8];
    u16* AL1 = &Ah[(srow + 64) * LSTR + sq8];
    u16* BL0 = &Bh[srow * LSTR + sq8];
    u16* BL1 = &Bh[(srow + 64) * LSTR + sq8];

    f32x4 acc[4][4];
    #pragma unroll
    for (int i = 0; i < 4; i++)
        #pragma unroll
        for (int j = 0; j < 4; j++) acc[i][j] = (f32x4){0.f, 0.f, 0.f, 0.f};

    // prologue: stage k0 = 0
    *(uint4*)AL0 = *(const uint4*)As0;
    *(uint4*)AL1 = *(const uint4*)As1;
    *(uint4*)BL0 = *(const uint4*)Bs0;
    *(uint4*)BL1 = *(const uint4*)Bs1;
    __syncthreads();

    for (int k0 = 0; k0 < DMODEL; k0 += 32) {
        const bool have = (k0 + 32) < DMODEL;
        uint4 na0, na1, nb0, nb1;
        if (have) {
            na0 = *(const uint4*)(As0 + k0 + 32);
            na1 = *(const uint4*)(As1 + k0 + 32);
            nb0 = *(const uint4*)(Bs0 + k0 + 32);
            nb1 = *(const uint4*)(Bs1 + k0 + 32);
        }

        f16x8 a_h[4], b_h[4];
        #pragma unroll
        for (int i = 0; i < 4; i++)
            a_h[i] = *(const f16x8*)&Ah[(wr * 64 + i * 16 + li) * LSTR + g * 8];
        #pragma unroll
        for (int j = 0; j < 4; j++)
            b_h[j] = *(const f16x8*)&Bh[(wc * 64 + j * 16 + li) * LSTR + g * 8];
        #pragma unroll
        for (int i = 0; i < 4; i++)
            #pragma unroll
            for (int j = 0; j < 4; j++)
                acc[i][j] = __builtin_amdgcn_mfma_f32_16x16x32_f16(
                    a_h[i], b_h[j], acc[i][j], 0, 0, 0);

        if (have) {
            __syncthreads();
            *(uint4*)AL0 = na0; *(uint4*)AL1 = na1;
            *(uint4*)BL0 = nb0; *(uint4*)BL1 = nb1;
            __syncthreads();
        }
    }

    if (z == 2) {
        // V^T epilogue: [B,H,Dk,S]; r-contiguous along S -> ushort4 stores
        #pragma unroll
        for (int i = 0; i < 4; i++) {
            int s_base = bm + wr * 64 + i * 16 + g * 4;
            int bb = s_base >> 11, s = s_base & 2047;
            #pragma unroll
            for (int j = 0; j < 4; j++) {
                int gcol = bn + wc * 64 + j * 16 + li;
                int hh = gcol >> 6, d = gcol & 63;
                long idx = (((long)(bb * NH + hh)) * DK + d) * S_LEN + s;
                *(ushort4*)&VT[idx] = make_ushort4(
                    f2h(acc[i][j][0]), f2h(acc[i][j][1]),
                    f2h(acc[i][j][2]), f2h(acc[i][j][3]));
            }
        }
    } else {
        u16* O = (z == 0) ? Qf : Kf;
        #pragma unroll
        for (int i = 0; i < 4; i++) {
            #pragma unroll
            for (int r = 0; r < 4; r++) {
                int grow = bm + wr * 64 + i * 16 + g * 4 + r;
                int bb = grow >> 11, s = grow & 2047;
                #pragma unroll
                for (int j = 0; j < 4; j++) {
                    int gcol = bn + wc * 64 + j * 16 + li;
                    int hh = gcol >> 6, d = gcol & 63;
                    long idx = (((long)(bb * NH + hh)) * S_LEN + s) * DK + d;
                    O[idx] = f2h(acc[i][j][r]);
                }
            }
        }
    }
}

// ------------------------- MFMA output GEMM (fp16) -------------------------
__global__ __launch_bounds__(256, 3) void gemm_out_mfma(
    const u16* __restrict__ Ab, const u16* __restrict__ WT,
    float* __restrict__ O)
{
    const u16* BT = WT + 3L * 1048576;   // wo fp16 plane
    __shared__ __align__(16) u16 Ah[128 * LSTR], Bh[128 * LSTR];

    const int tid = threadIdx.x;
    const int wv = tid >> 6, lane = tid & 63;
    const int g = lane >> 4, li = lane & 15;
    const int wr = wv >> 1, wc = wv & 1;
    const int bm = blockIdx.y * 128, bn = blockIdx.x * 128;

    const int srow = tid >> 2, sq8 = (tid & 3) * 8;
    const u16* As0 = &Ab[(long)(bm + srow) * DMODEL + sq8];
    const u16* As1 = &Ab[(long)(bm + srow + 64) * DMODEL + sq8];
    const u16* Bs0 = &BT[(long)(bn + srow) * DMODEL + sq8];
    const u16* Bs1 = &BT[(long)(bn + srow + 64) * DMODEL + sq8];
    u16* AL0 = &Ah[srow * LSTR + sq8];
    u16* AL1 = &Ah[(srow + 64) * LSTR + sq8];
    u16* BL0 = &Bh[srow * LSTR + sq8];
    u16* BL1 = &Bh[(srow + 64) * LSTR + sq8];

    f32x4 acc[4][4];
    #pragma unroll
    for (int i = 0; i < 4; i++)
        #pragma unroll
        for (int j = 0; j < 4; j++) acc[i][j] = (f32x4){0.f, 0.f, 0.f, 0.f};

    *(uint4*)AL0 = *(const uint4*)As0;
    *(uint4*)AL1 = *(const uint4*)As1;
    *(uint4*)BL0 = *(const uint4*)Bs0;
    *(uint4*)BL1 = *(const uint4*)Bs1;
    __syncthreads();

    for (int k0 = 0; k0 < DMODEL; k0 += 32) {
        const bool have = (k0 + 32) < DMODEL;
        uint4 na0, na1, nb0, nb1;
        if (have) {
            na0 = *(const uint4*)(As0 + k0 + 32);
            na1 = *(const uint4*)(As1 + k0 + 32);
            nb0 = *(const uint4*)(Bs0 + k0 + 32);
            nb1 = *(const uint4*)(Bs1 + k0 + 32);
        }

        f16x8 a_h[4], b_h[4];
        #pragma unroll
        for (int i = 0; i < 4; i++)
            a_h[i] = *(const f16x8*)&Ah[(wr * 64 + i * 16 + li) * LSTR + g * 8];
        #pragma unroll
        for (int j = 0; j < 4; j++)
            b_h[j] = *(const f16x8*)&Bh[(wc * 64 + j * 16 + li) * LSTR + g * 8];
        #pragma unroll
        for (int i = 0; i < 4; i++)
            #pragma unroll
            for (int j = 0; j < 4; j++)
                acc[i][j] = __builtin_amdgcn_mfma_f32_16x16x32_f16(
                    a_h[i], b_h[j], acc[i][j], 0, 0, 0);

        if (have) {
            __syncthreads();
            *(uint4*)AL0 = na0; *(uint4*)AL1 = na1;
            *(uint4*)BL0 = nb0; *(uint4*)BL1 = nb1;
            __syncthreads();
        }
    }

    #pragma unroll
    for (int i = 0; i < 4; i++)
        #pragma unroll
        for (int r = 0; r < 4; r++) {
            int grow = bm + wr * 64 + i * 16 + g * 4 + r;
            #pragma unroll
            for (int j = 0; j < 4; j++) {
                int gcol = bn + wc * 64 + j * 16 + li;
                O[(long)grow * DMODEL + gcol] = acc[i][j][r];
            }
        }
}

// ------------------------- MFMA flash attention (fp16, S^T softmax) --------
// Scores computed transposed: S^T = K·Q^T, so C-layout gives each lane ONE
// query (col = li) and 16 keys in regs.
// This version: T14 async-STAGE split (prefetch next K/V/bias tile to regs,
// write LDS after the read-barrier), exact rescale-skip (alpha==1 tiles),
// exp2-domain softmax (bias table pre-scaled by log2e), tree reductions,
// setprio(1) around MFMA clusters.
#define APAD 72

__global__ __launch_bounds__(256, 4) void attn_mfma(
    const u16* __restrict__ Qf, const u16* __restrict__ Kf,
    const u16* __restrict__ VT, const float* __restrict__ tab,
    u16* __restrict__ ctxb)
{
    __shared__ __align__(16) u16 Ks[64 * APAD];
    __shared__ __align__(16) u16 Vs[64 * APAD];    // [dim][key]
    __shared__ __align__(16) u16 Ps[64 * APAD];    // [q][key], wave-private slabs
    __shared__ float biasS[128];

    const int tid = threadIdx.x;
    const int wv = tid >> 6, lane = tid & 63;
    const int g = lane >> 4, li = lane & 15;
    const int qblk = blockIdx.x & 31;
    const int h = (blockIdx.x >> 5) & 15;
    const int b = blockIdx.x >> 9;
    const int q0 = qblk * 64;
    const long bh = b * NH + h;
    const int qloc = wv * 16 + li;     // this lane's query (within block)

    const u16* KhG = Kf + bh * (S_LEN * DK);
    const u16* VtG = VT + bh * (DK * S_LEN);
    const float* th = tab + h * 4096;

    const int srow = tid >> 3, sc8 = (tid & 7) * 8;   // staging coords

    f16x8 q0f, q1f;
    {
        long qrow = bh * S_LEN + q0 + qloc;
        const u16* ph = Qf + qrow * DK + g * 8;
        q0f = *(const f16x8*)ph;  q1f = *(const f16x8*)(ph + 32);
    }

    // ---- prologue: stage tile 0 ----
    *(uint4*)&Ks[srow * APAD + sc8] =
        *(const uint4*)&KhG[(long)srow * DK + sc8];
    *(uint4*)&Ks[(srow + 32) * APAD + sc8] =
        *(const uint4*)&KhG[(long)(srow + 32) * DK + sc8];
    *(uint4*)&Vs[srow * APAD + sc8] =
        *(const uint4*)&VtG[(long)srow * S_LEN + sc8];
    *(uint4*)&Vs[(srow + 32) * APAD + sc8] =
        *(const uint4*)&VtG[(long)(srow + 32) * S_LEN + sc8];
    if (tid < 128) {
        int idx = tid - 63 - q0 + 2048;
        idx = idx < 0 ? 0 : (idx > 4095 ? 4095 : idx);
        biasS[tid] = th[idx];
    }
    __syncthreads();

    f32x4 Oc[4];
    #pragma unroll
    for (int n = 0; n < 4; n++) Oc[n] = (f32x4){0.f, 0.f, 0.f, 0.f};
    float mP = -1e30f, lR = 0.f;   // mP in log2 domain

    for (int kt0 = 0; kt0 < S_LEN; kt0 += 64) {
        const int ktn = kt0 + 64;
        const bool havenext = ktn < S_LEN;

        // ---- T14: issue next tile's global loads NOW, consume after barrier
        uint4 nk0, nk1, nv0, nv1; float nb = 0.f;
        if (havenext) {
            nk0 = *(const uint4*)&KhG[(long)(ktn + srow) * DK + sc8];
            nk1 = *(const uint4*)&KhG[(long)(ktn + srow + 32) * DK + sc8];
            nv0 = *(const uint4*)&VtG[(long)srow * S_LEN + ktn + sc8];
            nv1 = *(const uint4*)&VtG[(long)(srow + 32) * S_LEN + ktn + sc8];
            if (tid < 128) {
                int idx = ktn + tid - 63 - q0 + 2048;
                idx = idx < 0 ? 0 : (idx > 4095 ? 4095 : idx);
                nb = th[idx];
            }
        }

        // ---- scores transposed: S^T[key][q] = K·Q^T ----
        f32x4 Sa[4];
        __builtin_amdgcn_s_setprio(1);
        #pragma unroll
        for (int m = 0; m < 4; m++) {
            const u16* kp = &Ks[(m * 16 + li) * APAD + g * 8];
            f16x8 k0 = *(const f16x8*)kp, k1 = *(const f16x8*)(kp + 32);
            f32x4 s = (f32x4){0.f, 0.f, 0.f, 0.f};
            s = __builtin_amdgcn_mfma_f32_16x16x32_f16(k0, q0f, s, 0, 0, 0);
            s = __builtin_amdgcn_mfma_f32_16x16x32_f16(k1, q1f, s, 0, 0, 0);
            Sa[m] = s;   // rows: key = m*16 + g*4 + r ; col: query = li
        }
        __builtin_amdgcn_s_setprio(0);

        // ---- fold bias add + log2e scale into one fma (table pre-scaled) --
        #pragma unroll
        for (int m = 0; m < 4; m++)
            #pragma unroll
            for (int r = 0; r < 4; r++)
                Sa[m][r] = fmaf(Sa[m][r], LOG2E,
                                biasS[m * 16 + g * 4 + r + 63 - qloc]);

        // ---- tile max: tree reduce 16 in-reg, then 2 shfl steps ----
        float mm[4];
        #pragma unroll
        for (int m = 0; m < 4; m++)
            mm[m] = fmaxf(fmaxf(Sa[m][0], Sa[m][1]),
                          fmaxf(Sa[m][2], Sa[m][3]));
        float pm = fmaxf(fmaxf(mm[0], mm[1]), fmaxf(mm[2], mm[3]));
        pm = fmaxf(pm, __shfl_xor(pm, 16));
        pm = fmaxf(pm, __shfl_xor(pm, 32));

        // ---- exact rescale-skip: alpha==1 when no query's max grew ----
        if (__any(pm > mP)) {
            float mn = fmaxf(mP, pm);
            float alpha = __builtin_amdgcn_exp2f(mP - mn);
            mP = mn;
            lR *= alpha;
            float aO[4];
            #pragma unroll
            for (int r = 0; r < 4; r++) aO[r] = __shfl(alpha, g * 4 + r);
            #pragma unroll
            for (int n = 0; n < 4; n++)
                #pragma unroll
                for (int r = 0; r < 4; r++) Oc[n][r] *= aO[r];
        }

        // ---- P = exp2(t - mP); tree-sum ----
        float sm[4];
        #pragma unroll
        for (int m = 0; m < 4; m++) {
            #pragma unroll
            for (int r = 0; r < 4; r++)
                Sa[m][r] = __builtin_amdgcn_exp2f(Sa[m][r] - mP);
            sm[m] = (Sa[m][0] + Sa[m][1]) + (Sa[m][2] + Sa[m][3]);
        }
        float ls = (sm[0] + sm[1]) + (sm[2] + sm[3]);
        ls += __shfl_xor(ls, 16);
        ls += __shfl_xor(ls, 32);
        lR += ls;

        // ---- P -> LDS [q][key], 8B stores; wave-private rows, no barrier --
        #pragma unroll
        for (int m = 0; m < 4; m++)
            *(ushort4*)&Ps[qloc * APAD + m * 16 + g * 4] = make_ushort4(
                f2h(Sa[m][0]), f2h(Sa[m][1]), f2h(Sa[m][2]), f2h(Sa[m][3]));

        // ---- O += P · V ----
        {
            const u16* pp = &Ps[qloc * APAD + g * 8];
            f16x8 p0 = *(const f16x8*)pp, p1 = *(const f16x8*)(pp + 32);
            __builtin_amdgcn_s_setprio(1);
            #pragma unroll
            for (int n = 0; n < 4; n++) {
                const u16* vp = &Vs[(n * 16 + li) * APAD + g * 8];
                f16x8 v0 = *(const f16x8*)vp, v1 = *(const f16x8*)(vp + 32);
                Oc[n] = __builtin_amdgcn_mfma_f32_16x16x32_f16(p0, v0, Oc[n], 0, 0, 0);
                Oc[n] = __builtin_amdgcn_mfma_f32_16x16x32_f16(p1, v1, Oc[n], 0, 0, 0);
            }
            __builtin_amdgcn_s_setprio(0);
        }

        // ---- write-late: commit prefetched tile after read-barrier ----
        if (havenext) {
            __syncthreads();   // all waves done with Ks/Vs
            *(uint4*)&Ks[srow * APAD + sc8] = nk0;
            *(uint4*)&Ks[(srow + 32) * APAD + sc8] = nk1;
            *(uint4*)&Vs[srow * APAD + sc8] = nv0;
            *(uint4*)&Vs[(srow + 32) * APAD + sc8] = nv1;
            if (tid < 128) biasS[tid] = nb;
            __syncthreads();   // staged data visible
        }
    }

    float linv = 1.0f / lR;
    float iv[4];
    #pragma unroll
    for (int r = 0; r < 4; r++) iv[r] = __shfl(linv, g * 4 + r);
    #pragma unroll
    for (int n = 0; n < 4; n++)
        #pragma unroll
        for (int r = 0; r < 4; r++)
            ctxb[((long)(b * S_LEN + q0 + wv * 16 + g * 4 + r)) * DMODEL
                 + h * DK + n * 16 + li] = f2h(Oc[n][r] * iv[r]);
}

// ------------------------- launcher ----------------------------------------
extern "C" void kernel_launch(void* const* d_in, const int* in_sizes, int n_in,
                              void* d_out, int out_size, void* d_ws, size_t ws_size,
                              hipStream_t stream)
{
    const float* x    = (const float*)d_in[0];
    const float* wq   = (const float*)d_in[1];
    const float* wk   = (const float*)d_in[2];
    const float* wv   = (const float*)d_in[3];
    const float* wo   = (const float*)d_in[4];
    const float* rel  = (const float*)d_in[5];

    u16* W0 = (u16*)d_ws;
    u16* Xf  = W0;                          // fp16 x         (8 MB)
    u16* Qf  = W0 + 4194304;                // fp16 [B,H,S,Dk]
    u16* Kf  = W0 + 8388608;
    u16* VT  = W0 + 12582912;               // fp16 [B,H,Dk,S]
    u16* WT  = W0 + 16777216;               // 4 fp16 planes [n][k] (8 MB)
    float* tab = (float*)(W0 + 20971520);   // [16,4096] fp32 (pre-scaled log2e)
    u16* ctxb = Xf;                         // alias: Xf dead after gemm_qkv

    bias_table_kernel<<<dim3(256), dim3(256), 0, stream>>>(rel, tab);
    convert_x<<<dim3(2048), dim3(256), 0, stream>>>(x, Xf);
    convert_wT<<<dim3(16, 16, 4), dim3(256), 0, stream>>>(wq, wk, wv, wo, WT);
    gemm_qkv_mfma<<<dim3(8, 32, 3), dim3(256), 0, stream>>>(Xf, WT, Qf, Kf, VT);
    attn_mfma<<<dim3(1024), dim3(256), 0, stream>>>(Qf, Kf, VT, tab, ctxb);
    gemm_out_mfma<<<dim3(8, 32), dim3(256), 0, stream>>>(ctxb, WT, (float*)d_out);
}